// Round 9
// baseline (217.592 us; speedup 1.0000x reference)
//
#include <hip/hip_runtime.h>
#include <hip/hip_bf16.h>

#define BATCH 4
#define CCH   256
#define HWHW  4096
#define NSP   256
#define NHEAD 8
#define SCALE 0.17677669529663689f
#define PLANE 1048576L

typedef short bf16x8 __attribute__((ext_vector_type(8)));
typedef float f32x4  __attribute__((ext_vector_type(4)));

// ---------------------------------------------------------------------------
// Fused LayerNorm -> xn_cn [b][c][n] + xn_nc [b][n][c] (bf16).
// Blocks 0..255: LN (64 px/block, float4 x reads for 4x MLP).  256..259: W casts.
__global__ __launch_bounds__(256)
void ln_fused_kernel(const float* __restrict__ x, const float* __restrict__ w,
                     const float* __restrict__ bb,
                     const float* __restrict__ Wq, const float* __restrict__ Wk,
                     const float* __restrict__ Wv, const float* __restrict__ Wsp,
                     __hip_bfloat16* __restrict__ xn_cn,
                     __hip_bfloat16* __restrict__ xn_nc,
                     __hip_bfloat16* __restrict__ wbf)
{
    __shared__ __hip_bfloat16 xs[256][80];     // [c][px], pitch 80 bf16
    __shared__ float ps[16][64], pss[16][64];
    __shared__ float mus[64], rstds[64];
    __shared__ float wls[256], bls[256];
    int blk = blockIdx.x;
    int t = threadIdx.x;
    if (blk >= 256) {                          // weight casts
        int sel = blk - 256;
        const float* src = (sel == 0) ? Wq : (sel == 1) ? Wk : (sel == 2) ? Wv : Wsp;
        __hip_bfloat16* dst = wbf + sel * 65536;
        for (int i = t * 4; i < 65536; i += 1024) {
            float4 f = *(const float4*)(src + i);
            __hip_bfloat16 p[4];
            p[0] = __float2bfloat16(f.x); p[1] = __float2bfloat16(f.y);
            p[2] = __float2bfloat16(f.z); p[3] = __float2bfloat16(f.w);
            *(int2*)(dst + i) = *(int2*)p;
        }
        return;
    }
    int b = blk >> 6;
    int n0 = (blk & 63) * 64;
    int px4 = t & 15, cg = t >> 4;             // 16 px-quads x 16 ch-groups
    wls[t] = w[t]; bls[t] = bb[t];
    long base = (long)b * CCH * HWHW + n0 + px4 * 4;
    float s0 = 0.f, s1 = 0.f, s2 = 0.f, s3 = 0.f;
    float q0 = 0.f, q1 = 0.f, q2 = 0.f, q3 = 0.f;
#pragma unroll
    for (int j = 0; j < 16; ++j) {
        int c = cg * 16 + j;
        float4 f = *(const float4*)(x + base + (long)c * HWHW);
        s0 += f.x; s1 += f.y; s2 += f.z; s3 += f.w;
        q0 += f.x * f.x; q1 += f.y * f.y; q2 += f.z * f.z; q3 += f.w * f.w;
        __hip_bfloat16 p[4];
        p[0] = __float2bfloat16(f.x); p[1] = __float2bfloat16(f.y);
        p[2] = __float2bfloat16(f.z); p[3] = __float2bfloat16(f.w);
        *(int2*)&xs[c][px4 * 4] = *(int2*)p;
    }
    *(float4*)&ps[cg][px4 * 4]  = float4{s0, s1, s2, s3};
    *(float4*)&pss[cg][px4 * 4] = float4{q0, q1, q2, q3};
    __syncthreads();
    if (t < 64) {
        float S = 0.f, SS = 0.f;
#pragma unroll
        for (int g = 0; g < 16; ++g) { S += ps[g][t]; SS += pss[g][t]; }
        float mu = S * (1.f / 256.f);
        float var = SS * (1.f / 256.f) - mu * mu;
        mus[t] = mu; rstds[t] = rsqrtf(var + 1e-6f);
    }
    __syncthreads();
    float mu[4], rst[4];
#pragma unroll
    for (int i = 0; i < 4; ++i) { mu[i] = mus[px4 * 4 + i]; rst[i] = rstds[px4 * 4 + i]; }
#pragma unroll
    for (int j = 0; j < 16; ++j) {
        int c = cg * 16 + j;
        __hip_bfloat16 p[4];
        *(int2*)p = *(const int2*)&xs[c][px4 * 4];
        float wc = wls[c], bc = bls[c];
#pragma unroll
        for (int i = 0; i < 4; ++i)
            p[i] = __float2bfloat16(((float)p[i] - mu[i]) * rst[i] * wc + bc);
        *(int2*)&xs[c][px4 * 4] = *(int2*)p;
    }
    __syncthreads();
    // xn_cn store: [c][n] row-contiguous b128
#pragma unroll
    for (int i = 0; i < 8; ++i) {
        int idx = t + i * 256;
        int c = idx >> 3, seg = idx & 7;
        *(int4*)(xn_cn + (long)(b * CCH + c) * HWHW + n0 + seg * 8) =
            *(const int4*)&xs[c][seg * 8];
    }
    // xn_nc store: [n][c], coalesced (consecutive t -> consecutive 16B)
#pragma unroll
    for (int i = 0; i < 8; ++i) {
        int idx = t + i * 256;
        int px = idx >> 5, g8 = idx & 31;
        short pack[8];
#pragma unroll
        for (int j = 0; j < 8; ++j) {
            __hip_bfloat16 v = xs[g8 * 8 + j][px];
            pack[j] = *(short*)&v;
        }
        *(int4*)(xn_nc + ((long)b * HWHW + n0 + px) * CCH + g8 * 8) = *(int4*)pack;
    }
}

// ---------------------------------------------------------------------------
// Deterministic split-K(8) reduction -> stoken_bf; blocks 0..3 also reduce
// the rowsum partials -> rs[b*256+m].
__global__ __launch_bounds__(256)
void reduce8_cast_kernel(const float* __restrict__ part, const float* __restrict__ rsPart,
                         __hip_bfloat16* __restrict__ out, float* __restrict__ rs)
{
    int i = blockIdx.x * 256 + threadIdx.x;   // 262144
    if (blockIdx.x < 4) {
        int b = i >> 8, m = i & 255;
        float s = 0.f;
#pragma unroll
        for (int ch = 0; ch < 8; ++ch) s += rsPart[((b * 8 + ch) << 8) + m];
        rs[i] = s;
    }
    int b = i >> 16, idx = i & 65535;
    long base = (long)b * 8 * 65536 + idx;
    float s = 0.f;
#pragma unroll
    for (int ch = 0; ch < 8; ++ch) s += part[base + (long)ch * 65536];
    out[i] = __float2bfloat16(s);
}

// ---------------------------------------------------------------------------
// bf16 MFMA NT GEMM, software-pipelined.  C[m][n] = sum_k A[m][k]*B[n][k].
// OUTK: 0=f32, 1=bf16.  ROWSCALE: /(rowScale[m]+1e-16).  A32: fp32 A inline-cast.
// ROWSUM: emit rsPart[z*256+m] (ones-column MFMA trick).
template <int OUTK, bool ROWSCALE, bool A32, bool ROWSUM>
__global__ __launch_bounds__(256)
void mfma_gemm_nt(const void* __restrict__ Aptr, const __hip_bfloat16* __restrict__ B,
                  void* __restrict__ Cptr, int N, int K, int kChunk, int kShift,
                  long aStrideZ, long bStrideZ, long cStrideZ,
                  const float* __restrict__ rowScale, long sStrideZ,
                  float* __restrict__ rsPart)
{
    __shared__ __hip_bfloat16 Asm[4 * 64 * 8];
    __shared__ __hip_bfloat16 Bsm[4 * 64 * 8];
    int z = blockIdx.z;
    int b = z >> kShift;
    int ch = z & ((1 << kShift) - 1);
    int t = threadIdx.x;
    int lane = t & 63, w = t >> 6;
    int l15 = lane & 15, quad = lane >> 4;
    int Mt = blockIdx.y * 64, Nt = blockIdx.x * 64;

    const float* aSrcF = A32 ? ((const float*)Aptr + b * aStrideZ + (long)ch * kChunk
                                + (long)(Mt + w * 16 + l15) * K + quad * 8) : nullptr;
    const __hip_bfloat16* aSrcB = A32 ? nullptr :
        ((const __hip_bfloat16*)Aptr + b * aStrideZ + (long)ch * kChunk
         + (long)(Mt + w * 16 + l15) * K + quad * 8);
    const __hip_bfloat16* bSrc = B + b * bStrideZ + (long)ch * kChunk
        + (long)(Nt + w * 16 + l15) * K + quad * 8;
    __hip_bfloat16* aDst = &Asm[t * 8];
    __hip_bfloat16* bDst = &Bsm[t * 8];

    f32x4 acc00 = {0.f,0.f,0.f,0.f}, acc01 = acc00, acc10 = acc00, acc11 = acc00;
    f32x4 rs0 = acc00, rs1 = acc00;
    bf16x8 onesf;
    { short o = (l15 == 0) ? (short)0x3F80 : (short)0;
      onesf = bf16x8{o, o, o, o, o, o, o, o}; }
    int wm = (w & 1) * 2, wn = (w >> 1) * 2;

    float4 aF0, aF1; int4 aReg, bReg;
    if (A32) { aF0 = ((const float4*)aSrcF)[0]; aF1 = ((const float4*)aSrcF)[1]; }
    else aReg = *(const int4*)aSrcB;
    bReg = *(const int4*)bSrc;

    for (int k0 = 0; k0 < kChunk; k0 += 32) {
        if (A32) {
            __hip_bfloat16 tmp[8];
            tmp[0]=__float2bfloat16(aF0.x); tmp[1]=__float2bfloat16(aF0.y);
            tmp[2]=__float2bfloat16(aF0.z); tmp[3]=__float2bfloat16(aF0.w);
            tmp[4]=__float2bfloat16(aF1.x); tmp[5]=__float2bfloat16(aF1.y);
            tmp[6]=__float2bfloat16(aF1.z); tmp[7]=__float2bfloat16(aF1.w);
            *(int4*)aDst = *(const int4*)tmp;
        } else {
            *(int4*)aDst = aReg;
        }
        *(int4*)bDst = bReg;
        __syncthreads();
        if (k0 + 32 < kChunk) {               // prefetch next tile
            bSrc += 32;
            if (A32) { aSrcF += 32; aF0 = ((const float4*)aSrcF)[0]; aF1 = ((const float4*)aSrcF)[1]; }
            else     { aSrcB += 32; aReg = *(const int4*)aSrcB; }
            bReg = *(const int4*)bSrc;
        }
        bf16x8 a0 = ((const bf16x8*)Asm)[wm * 64 + lane];
        bf16x8 a1 = ((const bf16x8*)Asm)[(wm + 1) * 64 + lane];
        bf16x8 b0 = ((const bf16x8*)Bsm)[wn * 64 + lane];
        bf16x8 b1 = ((const bf16x8*)Bsm)[(wn + 1) * 64 + lane];
        acc00 = __builtin_amdgcn_mfma_f32_16x16x32_bf16(a0, b0, acc00, 0, 0, 0);
        acc01 = __builtin_amdgcn_mfma_f32_16x16x32_bf16(a0, b1, acc01, 0, 0, 0);
        acc10 = __builtin_amdgcn_mfma_f32_16x16x32_bf16(a1, b0, acc10, 0, 0, 0);
        acc11 = __builtin_amdgcn_mfma_f32_16x16x32_bf16(a1, b1, acc11, 0, 0, 0);
        if (ROWSUM) {
            rs0 = __builtin_amdgcn_mfma_f32_16x16x32_bf16(a0, onesf, rs0, 0, 0, 0);
            rs1 = __builtin_amdgcn_mfma_f32_16x16x32_bf16(a1, onesf, rs1, 0, 0, 0);
        }
        __syncthreads();
    }
    if (ROWSUM && blockIdx.x == 0 && (w >> 1) == 0 && l15 == 0) {
#pragma unroll
        for (int r = 0; r < 4; ++r) {
            rsPart[(long)z * 256 + Mt + wm * 16 + quad * 4 + r]       = rs0[r];
            rsPart[(long)z * 256 + Mt + (wm + 1) * 16 + quad * 4 + r] = rs1[r];
        }
    }
    f32x4 accs[2][2] = {{acc00, acc01}, {acc10, acc11}};
#pragma unroll
    for (int i = 0; i < 2; ++i)
#pragma unroll
        for (int j = 0; j < 2; ++j)
#pragma unroll
            for (int r = 0; r < 4; ++r) {
                int m = Mt + (wm + i) * 16 + quad * 4 + r;
                int n = Nt + (wn + j) * 16 + l15;
                float val = accs[i][j][r];
                if (ROWSCALE) val /= (rowScale[(long)b * sStrideZ + m] + 1e-16f);
                long off = (long)z * cStrideZ + (long)m * N + n;
                if (OUTK == 0) ((float*)Cptr)[off] = val;
                else ((__hip_bfloat16*)Cptr)[off] = __float2bfloat16(val);
            }
}

// ---------------------------------------------------------------------------
// Stage-1 MFMA attention partials.  k lives in qk_nc at column offset 256.
// opart: [chunk][bh][col(33)][m(256)] bf16 (coalesced both ends).
__global__ __launch_bounds__(256)
void stage1_mfma(const __hip_bfloat16* __restrict__ qk_nc,
                 const __hip_bfloat16* __restrict__ v_cn,
                 const __hip_bfloat16* __restrict__ st_md,
                 __hip_bfloat16* __restrict__ opart)
{
    __shared__ __hip_bfloat16 Es[256 * 72];
    __shared__ __hip_bfloat16 sts[256 * 40];
    const int chunk = blockIdx.x, bh = blockIdx.y;
    const int b = bh >> 3, h = bh & 7;
    const int t = threadIdx.x, lane = t & 63, w = t >> 6;
    const int l15 = lane & 15, quad = lane >> 4;
    const int n0 = chunk * 256;

    {
        const int4* src = (const int4*)(st_md + ((long)(b * 256 + t)) * 256 + h * 32);
        int4* dst = (int4*)&sts[t * 40];
        dst[0] = src[0]; dst[1] = src[1]; dst[2] = src[2]; dst[3] = src[3];
    }
    __syncthreads();
    bf16x8 afrag[16];
#pragma unroll
    for (int mt = 0; mt < 16; ++mt)
        afrag[mt] = *(const bf16x8*)&sts[(mt * 16 + l15) * 40 + quad * 8];
    bf16x8 onesf;
    { short o = (l15 == 0) ? (short)0x3F80 : (short)0;
      onesf = bf16x8{o, o, o, o, o, o, o, o}; }

    f32x4 occ[4][3];
#pragma unroll
    for (int i = 0; i < 4; ++i)
#pragma unroll
        for (int j = 0; j < 3; ++j) occ[i][j] = f32x4{0.f,0.f,0.f,0.f};

    for (int sub = 0; sub < 4; ++sub) {
        const int nbase = n0 + sub * 64;
        bf16x8 kf = *(const bf16x8*)(qk_nc + ((long)b * 4096 + nbase + 16 * w + l15) * 512 + 256 + h * 32 + quad * 8);
#pragma unroll
        for (int mt = 0; mt < 16; ++mt) {
            f32x4 s = __builtin_amdgcn_mfma_f32_16x16x32_bf16(afrag[mt], kf, f32x4{0.f,0.f,0.f,0.f}, 0, 0, 0);
#pragma unroll
            for (int r = 0; r < 4; ++r)
                Es[(mt * 16 + quad * 4 + r) * 72 + 16 * w + l15] =
                    __float2bfloat16(__expf(s[r] * SCALE));
        }
        __syncthreads();
#pragma unroll
        for (int ks = 0; ks < 2; ++ks) {
            bf16x8 bf0 = *(const bf16x8*)(v_cn + ((long)(b * 256 + h * 32 + l15)) * 4096 + nbase + ks * 32 + quad * 8);
            bf16x8 bf1 = *(const bf16x8*)(v_cn + ((long)(b * 256 + h * 32 + 16 + l15)) * 4096 + nbase + ks * 32 + quad * 8);
#pragma unroll
            for (int mi = 0; mi < 4; ++mi) {
                bf16x8 af = *(const bf16x8*)&Es[(64 * w + mi * 16 + l15) * 72 + ks * 32 + quad * 8];
                occ[mi][0] = __builtin_amdgcn_mfma_f32_16x16x32_bf16(af, bf0, occ[mi][0], 0, 0, 0);
                occ[mi][1] = __builtin_amdgcn_mfma_f32_16x16x32_bf16(af, bf1, occ[mi][1], 0, 0, 0);
                occ[mi][2] = __builtin_amdgcn_mfma_f32_16x16x32_bf16(af, onesf, occ[mi][2], 0, 0, 0);
            }
        }
        __syncthreads();
    }
    __hip_bfloat16* tb = Es;
#pragma unroll
    for (int mi = 0; mi < 4; ++mi)
#pragma unroll
        for (int jt = 0; jt < 3; ++jt) {
            if (jt == 2 && l15 != 0) continue;
            int col = jt * 16 + l15;
#pragma unroll
            for (int r = 0; r < 4; ++r) {
                int m = 64 * w + mi * 16 + quad * 4 + r;
                tb[col * 264 + m] = __float2bfloat16(occ[mi][jt][r]);
            }
        }
    __syncthreads();
    int* og = (int*)(opart) + (long)(chunk * 32 + bh) * 4224;
    const int* tbi = (const int*)tb;
#pragma unroll
    for (int i = 0; i < 17; ++i) {
        int idx = t + i * 256;
        if (idx < 4224) {
            int row = idx >> 7, off = idx & 127;
            og[idx] = tbi[row * 132 + off];
        }
    }
}

// Merge stage-1 partials -> sout_bf[bh][d][m]
__global__ __launch_bounds__(256)
void merge1_kernel(const __hip_bfloat16* __restrict__ opart, __hip_bfloat16* __restrict__ sout)
{
    int t = blockIdx.x * 256 + threadIdx.x;   // 262144
    int m = t & 255;
    int d = (t >> 8) & 31;
    int bh = t >> 13;
    float num = 0.f, den = 0.f;
    for (int ch = 0; ch < 16; ++ch) {
        long base = (long)((ch * 32 + bh) * 33) * 256 + m;
        num += (float)opart[base + (long)d * 256];
        den += (float)opart[base + 32 * 256];
    }
    sout[(long)bh * 8192 + d * 256 + m] = __float2bfloat16(num / den);
}

// ---------------------------------------------------------------------------
// Depthwise 3x3 conv + scramble-transpose -> lepe_cn (final [b][c][n], bf16).
__global__ __launch_bounds__(256)
void lepe_conv_t_kernel(const __hip_bfloat16* __restrict__ v_cn,
                        const float* __restrict__ lw, const float* __restrict__ lb,
                        __hip_bfloat16* __restrict__ lepe_cn)
{
    __shared__ __hip_bfloat16 in_t[32 * 384];
    __shared__ __hip_bfloat16 tile_bf[256 * 33];
    __shared__ float wls[288], bls[32];
    const int bx = blockIdx.x;
    const int c0 = blockIdx.y * 32;
    const int b  = blockIdx.z;
    const int t = threadIdx.x;
    const int n0 = bx * 256, r0 = bx * 4;

    for (int i = t; i < 288; i += 256) wls[i] = lw[c0 * 9 + i];
    if (t < 32)  bls[t] = lb[c0 + t];
#pragma unroll
    for (int i = 0; i < 6; ++i) {
        int vi = t + i * 256;
        int ch = vi / 48;
        int off = (vi % 48) * 8;
        int g = (r0 - 1) * 64 + off;
        int4 val = {0, 0, 0, 0};
        if ((unsigned)g < 4096u)
            val = *(const int4*)(v_cn + (((long)(b * CCH + c0 + ch)) << 12) + g);
        *(int4*)&in_t[ch * 384 + off] = val;
    }
    __syncthreads();

    const int lane = t & 63, w = t >> 6;
#pragma unroll
    for (int i = 0; i < 8; ++i) {
        int ch = w * 8 + i;
        float cr[6], lf[6], rf[6];
#pragma unroll
        for (int rr = 0; rr < 6; ++rr) {
            cr[rr] = (float)in_t[ch * 384 + rr * 64 + lane];
            float lv = __shfl_up(cr[rr], 1);
            float rv = __shfl_down(cr[rr], 1);
            lf[rr] = (lane == 0) ? 0.f : lv;
            rf[rr] = (lane == 63) ? 0.f : rv;
        }
        float w0 = wls[ch*9+0], w1 = wls[ch*9+1], w2 = wls[ch*9+2];
        float w3 = wls[ch*9+3], w4 = wls[ch*9+4], w5 = wls[ch*9+5];
        float w6 = wls[ch*9+6], w7 = wls[ch*9+7], w8 = wls[ch*9+8];
        float bias = bls[ch];
#pragma unroll
        for (int r = 0; r < 4; ++r) {
            float acc = bias
                + lf[r]   * w0 + cr[r]   * w1 + rf[r]   * w2
                + lf[r+1] * w3 + cr[r+1] * w4 + rf[r+1] * w5
                + lf[r+2] * w6 + cr[r+2] * w7 + rf[r+2] * w8;
            tile_bf[(r * 64 + lane) * 33 + ch] = __float2bfloat16(acc);
        }
    }
    __syncthreads();
#pragma unroll
    for (int i = 0; i < 32; ++i) {
        int idx = t + i * 256;
        int nl = idx >> 5, cj = idx & 31;
        int sp = n0 + nl;
        lepe_cn[((long)(b * CCH + (sp >> 4)) << 12) + (nl & 15) * 256 + c0 + cj] =
            tile_bf[nl * 33 + cj];
    }
}

// ---------------------------------------------------------------------------
// Stage-2 MFMA attention + lepe add.  Writes final out[b][c][n].
__global__ __launch_bounds__(256)
void stage2_mfma(const __hip_bfloat16* __restrict__ qk_nc,
                 const __hip_bfloat16* __restrict__ st_md,
                 const __hip_bfloat16* __restrict__ sout_bf,
                 const __hip_bfloat16* __restrict__ lepe_cn,
                 float* __restrict__ out)
{
    __shared__ __hip_bfloat16 Es2[64 * 264];
    __shared__ __hip_bfloat16 sts[256 * 40];
    __shared__ __hip_bfloat16 sos[32 * 264];
    __shared__ float o_t[32 * 68];
    const int chunk = blockIdx.x, bh = blockIdx.y;
    const int b = bh >> 3, h = bh & 7;
    const int t = threadIdx.x, lane = t & 63, w = t >> 6;
    const int l15 = lane & 15, quad = lane >> 4;
    const int n0 = chunk * 256;

    {
        const int4* src = (const int4*)(st_md + ((long)(b * 256 + t)) * 256 + h * 32);
        int4* dst = (int4*)&sts[t * 40];
        dst[0] = src[0]; dst[1] = src[1]; dst[2] = src[2]; dst[3] = src[3];
    }
    {
        int row = t >> 3, seg = t & 7;
        const int4* src = (const int4*)(sout_bf + (long)bh * 8192 + row * 256 + seg * 32);
        int4* dst = (int4*)&sos[row * 264 + seg * 32];
        dst[0] = src[0]; dst[1] = src[1]; dst[2] = src[2]; dst[3] = src[3];
    }
    __syncthreads();
    bf16x8 stfrag[4];
#pragma unroll
    for (int mt = 0; mt < 4; ++mt)
        stfrag[mt] = *(const bf16x8*)&sts[(64 * w + mt * 16 + l15) * 40 + quad * 8];
    bf16x8 onesf;
    { short o = (l15 == 0) ? (short)0x3F80 : (short)0;
      onesf = bf16x8{o, o, o, o, o, o, o, o}; }

    for (int sub = 0; sub < 4; ++sub) {
        const int nbase = n0 + sub * 64;
#pragma unroll
        for (int nt = 0; nt < 4; ++nt) {
            bf16x8 qf = *(const bf16x8*)(qk_nc + ((long)b * 4096 + nbase + nt * 16 + l15) * 512 + h * 32 + quad * 8);
#pragma unroll
            for (int mt = 0; mt < 4; ++mt) {
                f32x4 s = __builtin_amdgcn_mfma_f32_16x16x32_bf16(qf, stfrag[mt], f32x4{0.f,0.f,0.f,0.f}, 0, 0, 0);
#pragma unroll
                for (int r = 0; r < 4; ++r)
                    Es2[(nt * 16 + quad * 4 + r) * 264 + 64 * w + mt * 16 + l15] =
                        __float2bfloat16(__expf(s[r] * SCALE));
            }
        }
        __syncthreads();
        f32x4 o0 = {0.f,0.f,0.f,0.f}, o1 = o0, o2 = o0;
#pragma unroll
        for (int ks = 0; ks < 8; ++ks) {
            bf16x8 af = *(const bf16x8*)&Es2[(16 * w + l15) * 264 + ks * 32 + quad * 8];
            bf16x8 b0 = *(const bf16x8*)&sos[(l15) * 264 + ks * 32 + quad * 8];
            bf16x8 b1 = *(const bf16x8*)&sos[(16 + l15) * 264 + ks * 32 + quad * 8];
            o0 = __builtin_amdgcn_mfma_f32_16x16x32_bf16(af, b0, o0, 0, 0, 0);
            o1 = __builtin_amdgcn_mfma_f32_16x16x32_bf16(af, b1, o1, 0, 0, 0);
            o2 = __builtin_amdgcn_mfma_f32_16x16x32_bf16(af, onesf, o2, 0, 0, 0);
        }
        __syncthreads();
#pragma unroll
        for (int r = 0; r < 4; ++r) {
            float den = __shfl(o2[r], lane & 48);
            float inv = 1.f / den;
            o_t[(l15) * 68 + 16 * w + quad * 4 + r]      = o0[r] * inv;
            o_t[(16 + l15) * 68 + 16 * w + quad * 4 + r] = o1[r] * inv;
        }
        __syncthreads();
        {
            int row = t >> 3, coff = (t & 7) * 8;
            long gb = ((long)(b * 256 + h * 32 + row)) * 4096 + nbase + coff;
            int4 lp4 = *(const int4*)(lepe_cn + gb);
            const __hip_bfloat16* lp = (const __hip_bfloat16*)&lp4;
            const float* sp = &o_t[row * 68 + coff];
            float4 r0, r1;
            r0.x = sp[0] + (float)lp[0]; r0.y = sp[1] + (float)lp[1];
            r0.z = sp[2] + (float)lp[2]; r0.w = sp[3] + (float)lp[3];
            r1.x = sp[4] + (float)lp[4]; r1.y = sp[5] + (float)lp[5];
            r1.z = sp[6] + (float)lp[6]; r1.w = sp[7] + (float)lp[7];
            *(float4*)(out + gb)     = r0;
            *(float4*)(out + gb + 4) = r1;
        }
        __syncthreads();
    }
}

// ---------------------------------------------------------------------------
extern "C" void kernel_launch(void* const* d_in, const int* in_sizes, int n_in,
                              void* d_out, int out_size, void* d_ws, size_t ws_size,
                              hipStream_t stream)
{
    const float* x    = (const float*)d_in[0];
    const float* aff  = (const float*)d_in[1];
    const float* nw   = (const float*)d_in[2];
    const float* nb   = (const float*)d_in[3];
    const float* Wq   = (const float*)d_in[4];
    const float* Wk   = (const float*)d_in[5];
    const float* Wv   = (const float*)d_in[6];
    const float* Wsp  = (const float*)d_in[7];
    const float* lw   = (const float*)d_in[8];
    const float* lb   = (const float*)d_in[9];
    float* out = (float*)d_out;

    float* ws = (float*)d_ws;
    const long P = PLANE;
    __hip_bfloat16* qk_nc  = (__hip_bfloat16*)(ws);           // [b][n][512] bf16
    __hip_bfloat16* v_cn   = (__hip_bfloat16*)(ws + 4 * P);
    __hip_bfloat16* xn_cn  = (__hip_bfloat16*)(ws + 6 * P);
    __hip_bfloat16* xn_nc  = (__hip_bfloat16*)(ws + 8 * P);
    __hip_bfloat16* lepe_cn= (__hip_bfloat16*)(ws + 10 * P);
    float* stoken_part = ws + 12 * P;                          // 32 x 65536 f32 = 2P
    __hip_bfloat16* opart = (__hip_bfloat16*)(ws + 14 * P);    // 16*32*33*256 bf16
    float* tail        = ws + 14 * P + 2162688;
    __hip_bfloat16* wbf       = (__hip_bfloat16*)tail;
    __hip_bfloat16* stoken_bf = (__hip_bfloat16*)(tail + 131072);
    __hip_bfloat16* st_md     = (__hip_bfloat16*)(tail + 262144);
    __hip_bfloat16* sout_bf   = (__hip_bfloat16*)(tail + 393216);
    float* rs      = tail + 524288;
    float* rs_part = tail + 525312;

    // 1. fused LayerNorm + weight casts
    ln_fused_kernel<<<260, 256, 0, stream>>>(x, nw, nb, Wq, Wk, Wv, Wsp,
                                             xn_cn, xn_nc, wbf);
    // 2. stoken partials (split-K=8, pipelined, inline fp32->bf16 A) + rowsums
    mfma_gemm_nt<0, false, true, true><<<dim3(4, 4, 32), 256, 0, stream>>>(
        aff, xn_cn, stoken_part, 256, 4096, 512, 3, P, P, 65536L, nullptr, 0, rs_part);
    // 3. reduce stoken + rowsums
    reduce8_cast_kernel<<<1024, 256, 0, stream>>>(stoken_part, rs_part, stoken_bf, rs);
    // 4. st_md = stoken·Wsp / (rs+eps)
    mfma_gemm_nt<1, true, false, false><<<dim3(4, 4, 4), 256, 0, stream>>>(
        stoken_bf, wbf + 3 * 65536, st_md, 256, 256, 256, 0, 65536L, 0L, 65536L, rs, 256L, nullptr);
    // 5. fused q+k
    mfma_gemm_nt<1, false, false, false><<<dim3(8, 64, 4), 256, 0, stream>>>(
        xn_nc, wbf, qk_nc, 512, 256, 256, 0, P, 0L, 2 * P, nullptr, 0, nullptr);
    // 6. v_cn
    mfma_gemm_nt<1, false, false, false><<<dim3(64, 4, 4), 256, 0, stream>>>(
        wbf + 2 * 65536, xn_nc, v_cn, 4096, 256, 256, 0, 0L, P, P, nullptr, 0, nullptr);
    // 7. lepe conv + scramble-transpose
    lepe_conv_t_kernel<<<dim3(16, 8, BATCH), 256, 0, stream>>>(v_cn, lw, lb, lepe_cn);
    // 8. stage-1 attention partials
    stage1_mfma<<<dim3(16, 32), 256, 0, stream>>>(qk_nc, v_cn, st_md, opart);
    // 9. merge -> sout_bf
    merge1_kernel<<<1024, 256, 0, stream>>>(opart, sout_bf);
    // 10. stage-2 attention + lepe add -> d_out
    stage2_mfma<<<dim3(16, 32), 256, 0, stream>>>(qk_nc, st_md, sout_bf, lepe_cn, out);
}